// Round 1
// baseline (278.199 us; speedup 1.0000x reference)
//
#include <hip/hip_runtime.h>

#define B_ 4
#define S_ 1024
#define F_ 512
#define H_ 16
#define D_ 32

typedef float f32x4 __attribute__((ext_vector_type(4)));
typedef short bf16x8 __attribute__((ext_vector_type(8)));

static __device__ __forceinline__ short f2b(float f) {
    union { float f; unsigned u; } x; x.f = f;
    unsigned u = x.u;
    unsigned r = u + 0x7fffu + ((u >> 16) & 1u);
    if ((u & 0x7f800000u) == 0x7f800000u && (u & 0x007fffffu)) r = u; // NaN passthrough
    return (short)(r >> 16);
}
static __device__ __forceinline__ float b2f(short s) {
    union { unsigned u; float f; } x; x.u = ((unsigned)(unsigned short)s) << 16;
    return x.f;
}

// ---------------- rel_table fp32 -> bf16 ----------------
__global__ void relconv_kernel(const float* __restrict__ rt, short* __restrict__ out, int n) {
    int i = blockIdx.x * 256 + threadIdx.x;
    if (i < n) out[i] = f2b(rt[i]);
}

// ---------------- MFMA GEMM: [4096x512] @ [512x512] ----------------
// A: fp32 (ABF16=false) or bf16 (true), row-major [M=4096][K=512]
// W: fp32 row-major [K=512][N=512]
// MODE 0: out fp32 plain [m][n]
// MODE 1: out bf16 heads  [b][h][s][d]   (m=b*1024+s, n=h*32+d)
// MODE 2: out bf16 headsT [b][h][d][s]
template<int MODE, bool ABF16>
__global__ __launch_bounds__(256)
void gemm_mfma(const void* __restrict__ Avoid, const float* __restrict__ W,
               void* __restrict__ out, float alpha)
{
    __shared__ __align__(16) short a_s[128 * 40]; // [128 rows][32 k] pad->40
    __shared__ __align__(16) short b_s[64 * 40];  // [64 n-rows][32 k] pad->40 (W transposed)
    const int t = threadIdx.x;
    const int w = t >> 6, lane = t & 63, l15 = lane & 15, quad = lane >> 4;
    const int wm = w & 1, wn = w >> 1;
    const int bm = blockIdx.y * 128, bn = blockIdx.x * 64;

    f32x4 acc[4][2] = {};

    for (int k0 = 0; k0 < 512; k0 += 32) {
        // ---- stage A tile (128x32) as bf16 ----
        if constexpr (!ABF16) {
            const float* A = (const float*)Avoid;
            #pragma unroll
            for (int i = 0; i < 4; ++i) {
                int lin = t + i * 256;           // 0..1023
                int r = lin >> 3, c4 = (lin & 7) * 4;
                float4 v = *(const float4*)(A + (long)(bm + r) * 512 + k0 + c4);
                unsigned p0 = ((unsigned)(unsigned short)f2b(v.x)) |
                              (((unsigned)(unsigned short)f2b(v.y)) << 16);
                unsigned p1 = ((unsigned)(unsigned short)f2b(v.z)) |
                              (((unsigned)(unsigned short)f2b(v.w)) << 16);
                unsigned* dst = (unsigned*)(a_s + r * 40 + c4);
                dst[0] = p0; dst[1] = p1;
            }
        } else {
            const short* A = (const short*)Avoid;
            #pragma unroll
            for (int i = 0; i < 2; ++i) {
                int lin = t + i * 256;           // 0..511
                int r = lin >> 2, c8 = (lin & 3) * 8;
                bf16x8 v = *(const bf16x8*)(A + (long)(bm + r) * 512 + k0 + c8);
                *(bf16x8*)(a_s + r * 40 + c8) = v;
            }
        }
        // ---- stage W tile transposed: b_s[n][k] ----
        #pragma unroll
        for (int i = 0; i < 8; ++i) {
            int lin = t + i * 256;               // 0..2047
            int n = lin & 63, kr = lin >> 6;     // kr 0..31
            float v = W[(long)(k0 + kr) * 512 + bn + n];
            b_s[n * 40 + kr] = f2b(v);
        }
        __syncthreads();

        bf16x8 af[4], bfr[2];
        #pragma unroll
        for (int mt = 0; mt < 4; ++mt)
            af[mt] = *(const bf16x8*)(a_s + (wm * 64 + mt * 16 + l15) * 40 + quad * 8);
        #pragma unroll
        for (int nt = 0; nt < 2; ++nt)
            bfr[nt] = *(const bf16x8*)(b_s + (wn * 32 + nt * 16 + l15) * 40 + quad * 8);
        #pragma unroll
        for (int mt = 0; mt < 4; ++mt)
            #pragma unroll
            for (int nt = 0; nt < 2; ++nt)
                acc[mt][nt] = __builtin_amdgcn_mfma_f32_16x16x32_bf16(af[mt], bfr[nt], acc[mt][nt], 0, 0, 0);
        __syncthreads();
    }

    // ---- epilogue ----
    #pragma unroll
    for (int mt = 0; mt < 4; ++mt) {
        #pragma unroll
        for (int nt = 0; nt < 2; ++nt) {
            #pragma unroll
            for (int r = 0; r < 4; ++r) {
                int m = bm + wm * 64 + mt * 16 + quad * 4 + r;
                int n = bn + wn * 32 + nt * 16 + l15;
                float v = acc[mt][nt][r] * alpha;
                if constexpr (MODE == 0) {
                    ((float*)out)[(long)m * 512 + n] = v;
                } else if constexpr (MODE == 1) {
                    int bb = m >> 10, s = m & 1023, hh = n >> 5, dd = n & 31;
                    ((short*)out)[((long)((bb * 16 + hh) * 1024 + s)) * 32 + dd] = f2b(v);
                } else {
                    int bb = m >> 10, s = m & 1023, hh = n >> 5, dd = n & 31;
                    ((short*)out)[((long)((bb * 16 + hh) * 32 + dd)) * 1024 + s] = f2b(v);
                }
            }
        }
    }
}

// ---------------- QR = Wrel @ qh per row (folds rel dense into query) ----------------
__global__ __launch_bounds__(256)
void qr_kernel(const short* __restrict__ qh, const float* __restrict__ wrel,
               short* __restrict__ qr)
{
    __shared__ float ws[32 * 33];
    __shared__ float qs[8 * 32];
    int t = threadIdx.x;
    for (int i = t; i < 1024; i += 256) ws[(i >> 5) * 33 + (i & 31)] = wrel[i];
    long row0 = (long)blockIdx.x * 8;
    int rloc = t >> 5, io = t & 31;
    qs[rloc * 32 + io] = b2f(qh[(row0 + rloc) * 32 + io]);
    __syncthreads();
    float acc = 0.f;
    #pragma unroll
    for (int j = 0; j < 32; ++j) acc += ws[io * 33 + j] * qs[rloc * 32 + j];
    qr[(row0 + rloc) * 32 + io] = f2b(acc);
}

// ---------------- fused attention ----------------
// one block = (b, h, 16-query tile); 4 waves, each owns k-range [w*256, w*256+256)
__global__ __launch_bounds__(256)
void attn_kernel(const short* __restrict__ qh, const short* __restrict__ qr,
                 const short* __restrict__ kh, const short* __restrict__ vt,
                 const short* __restrict__ relb, const int* __restrict__ mask,
                 short* __restrict__ ao)
{
    __shared__ __align__(16) char smem[55040];
    short* p_s     = (short*)smem;                    // [16][1032] bf16
    float* ct_s    = (float*)(smem + 33024);          // [4 waves][16][84] fp32
    float* o_s     = ct_s;                            // alias: [4][16][32] fp32 (used after ct done)
    float* red_max = (float*)(smem + 54528);          // [4][16]
    float* red_sum = (float*)(smem + 54528 + 256);    // [4][16]

    const int t = threadIdx.x;
    const int w = t >> 6;
    const int lane = t & 63;
    const int l15 = lane & 15;
    const int quad = lane >> 4;

    const int bid = blockIdx.x;
    const int qt = bid & 63;
    const int h  = (bid >> 6) & 15;
    const int b  = bid >> 10;
    const int q0 = qt * 16;
    const int bh = b * H_ + h;

    // A-frags: lane holds row (q0+l15), k = quad*8..+7 of D=32
    const long qbase = ((long)bh * S_ + q0 + l15) * D_ + quad * 8;
    const bf16x8 a_qh = *(const bf16x8*)(qh + qbase);
    const bf16x8 a_qr = *(const bf16x8*)(qr + qbase);

    const long kh_bh = (long)bh * S_ * D_;
    const long vt_bh = (long)bh * D_ * S_;
    float* ctw = ct_s + w * (16 * 84);

    f32x4 sc[16];

    // ---- score phase: QK^T + rel bias + mask ----
    for (int c = 0; c < 4; ++c) {
        const int kbase = w * 256 + c * 64;
        const int ub = kbase - q0 - 15 + S_;   // table row base for this chunk (always >=1)
        // rel bias tiles: Ct[q][u] = qr[q] . rel_table[ub+u]
        #pragma unroll
        for (int ut = 0; ut < 5; ++ut) {
            int u = ub + ut * 16 + l15;
            bf16x8 bre = *(const bf16x8*)(relb + (long)u * D_ + quad * 8);
            f32x4 z = {0.f, 0.f, 0.f, 0.f};
            f32x4 ct = __builtin_amdgcn_mfma_f32_16x16x32_bf16(a_qr, bre, z, 0, 0, 0);
            #pragma unroll
            for (int r = 0; r < 4; ++r)
                ctw[(quad * 4 + r) * 84 + ut * 16 + l15] = ct[r];
        }
        __syncthreads();
        #pragma unroll
        for (int kt = 0; kt < 4; ++kt) {
            int k0g = kbase + kt * 16;
            bf16x8 bk = *(const bf16x8*)(kh + kh_bh + (long)(k0g + l15) * D_ + quad * 8);
            f32x4 z = {0.f, 0.f, 0.f, 0.f};
            f32x4 acc = __builtin_amdgcn_mfma_f32_16x16x32_bf16(a_qh, bk, z, 0, 0, 0);
            int kcol = k0g + l15;
            #pragma unroll
            for (int r = 0; r < 4; ++r) {
                int qL = quad * 4 + r;
                // off = (kcol - (q0+qL) + S_) - ub = kt*16 + l15 + 15 - qL   (in [0,78])
                float s = acc[r] + ctw[qL * 84 + kt * 16 + l15 + 15 - qL];
                int mv = mask[((long)b * S_ + q0 + qL) * S_ + kcol];
                sc[c * 4 + kt][r] = (mv > 0) ? s : -__builtin_inff();
            }
        }
        __syncthreads();
    }

    // ---- softmax pass 1: row max ----
    #pragma unroll
    for (int r = 0; r < 4; ++r) {
        float mx = -__builtin_inff();
        #pragma unroll
        for (int i = 0; i < 16; ++i) mx = fmaxf(mx, sc[i][r]);
        #pragma unroll
        for (int off = 1; off < 16; off <<= 1) mx = fmaxf(mx, __shfl_xor(mx, off, 64));
        if (l15 == 0) red_max[w * 16 + quad * 4 + r] = mx;
    }
    __syncthreads();
    float m4[4];
    #pragma unroll
    for (int r = 0; r < 4; ++r) {
        int qL = quad * 4 + r;
        m4[r] = fmaxf(fmaxf(red_max[qL], red_max[16 + qL]),
                      fmaxf(red_max[32 + qL], red_max[48 + qL]));
    }
    // ---- softmax pass 2: exp, store P (bf16, A-layout rows), row sums ----
    float s4[4] = {0.f, 0.f, 0.f, 0.f};
    #pragma unroll
    for (int i = 0; i < 16; ++i) {
        int kcol = w * 256 + i * 16 + l15;
        #pragma unroll
        for (int r = 0; r < 4; ++r) {
            float p = __expf(sc[i][r] - m4[r]);
            s4[r] += p;
            p_s[(quad * 4 + r) * 1032 + kcol] = f2b(p);
        }
    }
    #pragma unroll
    for (int r = 0; r < 4; ++r) {
        float s = s4[r];
        #pragma unroll
        for (int off = 1; off < 16; off <<= 1) s += __shfl_xor(s, off, 64);
        if (l15 == 0) red_sum[w * 16 + quad * 4 + r] = s;
    }
    __syncthreads();

    // ---- PV: O[q][d] += P[q][k] * V[k][d], wave w covers k-chunks w,w+4,... ----
    f32x4 oacc[2] = {{0.f,0.f,0.f,0.f},{0.f,0.f,0.f,0.f}};
    #pragma unroll
    for (int i = 0; i < 8; ++i) {
        int kk = (w + i * 4) * 32;
        bf16x8 ap = *(const bf16x8*)(p_s + l15 * 1032 + kk + quad * 8);
        #pragma unroll
        for (int dt = 0; dt < 2; ++dt) {
            bf16x8 bv = *(const bf16x8*)(vt + vt_bh + (long)(dt * 16 + l15) * S_ + kk + quad * 8);
            oacc[dt] = __builtin_amdgcn_mfma_f32_16x16x32_bf16(ap, bv, oacc[dt], 0, 0, 0);
        }
    }
    #pragma unroll
    for (int dt = 0; dt < 2; ++dt)
        #pragma unroll
        for (int r = 0; r < 4; ++r)
            o_s[(w * 16 + quad * 4 + r) * 32 + dt * 16 + l15] = oacc[dt][r];
    __syncthreads();

    // ---- reduce partials across waves, normalize, store bf16 [b][s][h][d] ----
    #pragma unroll
    for (int it = 0; it < 2; ++it) {
        int idx = it * 256 + t;
        int qL = idx >> 5, d = idx & 31;
        float o = o_s[qL * 32 + d] + o_s[(16 + qL) * 32 + d] +
                  o_s[(32 + qL) * 32 + d] + o_s[(48 + qL) * 32 + d];
        float l = red_sum[qL] + red_sum[16 + qL] + red_sum[32 + qL] + red_sum[48 + qL];
        ao[((long)(b * S_ + q0 + qL) * H_ + h) * D_ + d] = f2b(o / l);
    }
}

extern "C" void kernel_launch(void* const* d_in, const int* in_sizes, int n_in,
                              void* d_out, int out_size, void* d_ws, size_t ws_size,
                              hipStream_t stream) {
    (void)in_sizes; (void)n_in; (void)out_size; (void)ws_size;
    const float* kv   = (const float*)d_in[0];
    const float* q    = (const float*)d_in[1];
    const int*   mask = (const int*)d_in[2];
    const float* Wq   = (const float*)d_in[3];
    const float* Wk   = (const float*)d_in[4];
    const float* Wv   = (const float*)d_in[5];
    const float* Wo   = (const float*)d_in[6];
    const float* rt   = (const float*)d_in[7];
    const float* Wrel = (const float*)d_in[8];

    char* ws = (char*)d_ws;
    short* qh   = (short*)(ws);                 // [B,H,S,D] bf16, 4MB
    short* kh   = (short*)(ws + (4u  << 20));   // [B,H,S,D]
    short* vt   = (short*)(ws + (8u  << 20));   // [B,H,D,S]
    short* qr   = (short*)(ws + (12u << 20));   // [B,H,S,D]
    short* ao   = (short*)(ws + (16u << 20));   // [B,S,H,D]
    short* relb = (short*)(ws + (20u << 20));   // [2049,32] bf16

    relconv_kernel<<<257, 256, 0, stream>>>(rt, relb, 2049 * 32);

    dim3 gg(8, 32); // N/64, M/128
    const float scale = 0.17677669529663687f;   // 1/sqrt(32), folded into QH (and thus QR)
    gemm_mfma<1, false><<<gg, 256, 0, stream>>>(q,  Wq, qh, scale);
    gemm_mfma<1, false><<<gg, 256, 0, stream>>>(kv, Wk, kh, 1.0f);
    gemm_mfma<2, false><<<gg, 256, 0, stream>>>(kv, Wv, vt, 1.0f);

    qr_kernel<<<8192, 256, 0, stream>>>(qh, Wrel, qr);

    attn_kernel<<<4096, 256, 0, stream>>>(qh, qr, kh, vt, relb, mask, ao);

    gemm_mfma<0, true><<<gg, 256, 0, stream>>>(ao, Wo, d_out, 1.0f);
}